// Round 7
// baseline (364.130 us; speedup 1.0000x reference)
//
#include <hip/hip_runtime.h>
#include <cstdint>
#include <cstddef>
#include <utility>

#define PI_F 3.14159265358979323846f

typedef __attribute__((ext_vector_type(8))) _Float16 half8;
typedef __attribute__((ext_vector_type(4))) float f32x4;

struct U4 { unsigned int w[4]; };

static __device__ __forceinline__ unsigned int packhalf2(float c, float s) {
  _Float16 hc = (_Float16)c, hs = (_Float16)s;
  unsigned short uc = __builtin_bit_cast(unsigned short, hc);
  unsigned short us = __builtin_bit_cast(unsigned short, hs);
  return (unsigned int)uc | ((unsigned int)us << 16);
}

static __device__ __forceinline__ void load16_lds(const void* g, void* l) {
  __builtin_amdgcn_global_load_lds(
      (const __attribute__((address_space(1))) unsigned int*)g,
      (__attribute__((address_space(3))) unsigned int*)l, 16, 0, 0);
}

// ---------------------------------------------------------------------------
// K1: MLP for all 2B samples -> hz[sample][16] = {h[0..7], z[0..6], 0}.
// Block 0 thread 0 also zero-inits scalars + out (replaces memset dispatches).
// ---------------------------------------------------------------------------
__global__ __launch_bounds__(256) void k_mlp(
    const float* __restrict__ x1, const float* __restrict__ x0,
    const float* __restrict__ W1, const float* __restrict__ b1,
    const float* __restrict__ W2, const float* __restrict__ b2,
    const float* __restrict__ W3, const float* __restrict__ b3,
    float* __restrict__ hz, int B, float* __restrict__ scalars,
    float* __restrict__ out) {
  int s = blockIdx.x * blockDim.x + threadIdx.x;
  if (blockIdx.x == 0 && threadIdx.x == 0) {
    scalars[0] = 0.f;
    scalars[1] = 0.f;
    out[0] = 0.f;
  }
  if (s >= 2 * B) return;
  const float* xp = (s < B) ? (x1 + (size_t)s * 8) : (x0 + (size_t)(s - B) * 8);
  float x[8];
#pragma unroll
  for (int k = 0; k < 8; k++) x[k] = xp[k];
  float a1[10];
#pragma unroll
  for (int o = 0; o < 10; o++) {
    float v = b1[o];
#pragma unroll
    for (int k = 0; k < 8; k++) v = fmaf(W1[o * 8 + k], x[k], v);
    a1[o] = fmaxf(v, 0.f);
  }
  float a2[10];
#pragma unroll
  for (int o = 0; o < 10; o++) {
    float v = b2[o];
#pragma unroll
    for (int k = 0; k < 10; k++) v = fmaf(W2[o * 10 + k], a1[k], v);
    a2[o] = fmaxf(v, 0.f);
  }
  float h[8];
#pragma unroll
  for (int o = 0; o < 8; o++) {
    float v = b3[o];
#pragma unroll
    for (int k = 0; k < 10; k++) v = fmaf(W3[o * 10 + k], a2[k], v);
    h[o] = v;
  }
  float outv[16];
#pragma unroll
  for (int k = 0; k < 8; k++) outv[k] = h[k];
#pragma unroll
  for (int k = 0; k < 7; k++) outv[8 + k] = (PI_F - h[k]) * (PI_F - h[k + 1]);
  outv[15] = 0.f;
  float4* dst = (float4*)(hz + (size_t)s * 16);
#pragma unroll
  for (int q = 0; q < 4; q++) dst[q] = ((float4*)outv)[q];
}

// ---------------------------------------------------------------------------
// K2: generate fp16 (cos,sin) pairs. A layout: [kb][256 rows][64 halfs],
// rows are 128B; within a row the 16B chunks are XOR-swizzled by (row&7):
//   physical_half(row, logical_half L) = L ^ ((row&7)<<3)
// Gray-code walk (one sign flip per row) + HW v_sin/v_cos in revolutions.
// ---------------------------------------------------------------------------
__global__ __launch_bounds__(256) void k_gen(const float* __restrict__ hz,
                                             _Float16* __restrict__ Ach) {
  __shared__ float hzl[32][17];  // padded: conflict-free column reads
  int kb = blockIdx.x, t = threadIdx.x;
  if (t < 128) {
    int smp = t >> 2, q = t & 3;
    const float4 v =
        *(const float4*)(hz + (size_t)(kb * 32 + smp) * 16 + q * 4);
    hzl[smp][q * 4 + 0] = v.x;
    hzl[smp][q * 4 + 1] = v.y;
    hzl[smp][q * 4 + 2] = v.z;
    hzl[smp][q * 4 + 3] = v.w;
  }
  __syncthreads();
  int s = t & 31, oct = t >> 5;  // sample-in-block, basis octet (wires 5-7)
  float h[8], z[7];
#pragma unroll
  for (int k = 0; k < 8; k++) h[k] = hzl[s][k];
#pragma unroll
  for (int k = 0; k < 7; k++) z[k] = hzl[s][8 + k];
  float S5 = (oct & 4) ? -1.f : 1.f;
  float S6 = (oct & 2) ? -1.f : 1.f;
  float S7 = (oct & 1) ? -1.f : 1.f;
  float sg[5] = {1.f, 1.f, 1.f, 1.f, 1.f};
  float phi = h[0] + h[1] + h[2] + h[3] + h[4] + S5 * h[5] + S6 * h[6] +
              S7 * h[7] + z[0] + z[1] + z[2] + z[3] + S5 * z[4] +
              S5 * S6 * z[5] + S6 * S7 * z[6];
  _Float16* dst = Ach + (size_t)kb * 16384;
  const int halfoff = (2 * s) ^ (oct << 3);

  auto emit = [&](int g, float ph) {
    float r = ph * 0.07957747154594767f;  // ph/(4*pi) revolutions
    r = r - floorf(r);
    float sv = __builtin_amdgcn_sinf(r);
    float cv = __builtin_amdgcn_cosf(r);
    *(unsigned int*)(dst + (size_t)(g * 8 + oct) * 64 + halfoff) =
        packhalf2(cv, sv);
  };

  emit(0, phi);
#pragma unroll
  for (int jj = 1; jj < 32; ++jj) {
    const int b = __builtin_ctz(jj);
    const int w = 4 - b;
    float nbl = (w == 0) ? 0.f : sg[w - 1] * z[w - 1];
    float nbr = (w == 4) ? S5 * z[4] : sg[w + 1] * z[w];
    phi -= 2.f * sg[w] * (h[w] + nbl + nbr);
    sg[w] = -sg[w];
    emit(jj ^ (jj >> 1), phi);
  }
}

// ---------------------------------------------------------------------------
// K3: triangular split-K MFMA GEMM -> per-slab partial tiles (no atomics).
// NP=1: diagonal tiles (A==B, 32 KiB LDS); NP=2: off-diagonal (64 KiB).
// ---------------------------------------------------------------------------
#define ZSLABS 256

template <int NP>
__global__ __launch_bounds__(256) void k_gemm_t(const _Float16* __restrict__ A,
                                                float* __restrict__ P,
                                                int kbPer) {
  __shared__ _Float16 lds[2][NP][128][64];
  int bx = blockIdx.x, z = blockIdx.y;
  int mbase, nbase, tile;
  if (NP == 1) {
    mbase = bx * 128;
    nbase = bx * 128;
    tile = bx * 2;
  } else {
    mbase = 0;
    nbase = 128;
    tile = 1;
  }
  int t = threadIdx.x, wave = t >> 6, lane = t & 63;
  int wm = wave >> 1, wn = wave & 1;
  unsigned int reMask = (z < ZSLABS / 2) ? 0u : 0x80008000u;
  unsigned int imMask = (z < ZSLABS / 2) ? 0x80000000u : 0x00008000u;
  int kb0 = z * kbPer;

  auto stage = [&](int it, int buf) {
    size_t kb = (size_t)(kb0 + it);
    const char* gA = (const char*)A + kb * 32768 + (size_t)mbase * 128;
    char* lA = (char*)&lds[buf][0][0][0];
#pragma unroll
    for (int q = 0; q < 4; q++) {
      int woff = wave * 4096 + q * 1024;
      load16_lds(gA + woff + lane * 16, lA + woff);
    }
    if (NP == 2) {
      const char* gB = (const char*)A + kb * 32768 + (size_t)nbase * 128;
      char* lB = (char*)&lds[buf][NP - 1][0][0];
#pragma unroll
      for (int q = 0; q < 4; q++) {
        int woff = wave * 4096 + q * 1024;
        load16_lds(gB + woff + lane * 16, lB + woff);
      }
    }
  };

  f32x4 accR[4][4] = {};
  f32x4 accI[4][4] = {};
  stage(0, 0);
  for (int it = 0; it < kbPer; ++it) {
    __syncthreads();
    if (it + 1 < kbPer) stage(it + 1, (it + 1) & 1);
    int buf = it & 1;
#pragma unroll
    for (int kk = 0; kk < 2; kk++) {
      int cbase = kk * 4 + (lane >> 4);
      half8 af[4], bfr[4], bfi[4];
#pragma unroll
      for (int fm = 0; fm < 4; fm++) {
        int r = wm * 64 + fm * 16 + (lane & 15);
        af[fm] = *(const half8*)&lds[buf][0][r][(cbase ^ (r & 7)) << 3];
      }
#pragma unroll
      for (int fn = 0; fn < 4; fn++) {
        int r = wn * 64 + fn * 16 + (lane & 15);
        half8 bv = *(const half8*)&lds[buf][NP - 1][r][(cbase ^ (r & 7)) << 3];
        U4 u = __builtin_bit_cast(U4, bv), ur, ui;
#pragma unroll
        for (int q = 0; q < 4; q++) {
          unsigned int xv = u.w[q];
          ur.w[q] = xv ^ reMask;
          ui.w[q] = ((xv << 16) | (xv >> 16)) ^ imMask;
        }
        bfr[fn] = __builtin_bit_cast(half8, ur);
        bfi[fn] = __builtin_bit_cast(half8, ui);
      }
#pragma unroll
      for (int fm = 0; fm < 4; fm++)
#pragma unroll
        for (int fn = 0; fn < 4; fn++) {
          accR[fm][fn] = __builtin_amdgcn_mfma_f32_16x16x32_f16(
              af[fm], bfr[fn], accR[fm][fn], 0, 0, 0);
          accI[fm][fn] = __builtin_amdgcn_mfma_f32_16x16x32_f16(
              af[fm], bfi[fn], accI[fm][fn], 0, 0, 0);
        }
    }
  }
  float* PR = P + ((size_t)(tile * ZSLABS + z) * 2) * 16384;
  float* PI = PR + 16384;
  int r4 = (lane >> 4) * 4, cj = lane & 15;
#pragma unroll
  for (int fm = 0; fm < 4; fm++)
#pragma unroll
    for (int fn = 0; fn < 4; fn++)
#pragma unroll
      for (int r = 0; r < 4; r++) {
        int li = wm * 64 + fm * 16 + r4 + r;
        int lj = wn * 64 + fn * 16 + cj;
        PR[li * 128 + lj] = accR[fm][fn][r];
        PI[li * 128 + lj] = accI[fm][fn][r];
      }
}

// ---------------------------------------------------------------------------
// K4: reduce partials -> Hermitian A (scaled), accumulate ||A||_F^2.
// 4-way split accumulators for ILP (Guideline 7).
// ---------------------------------------------------------------------------
__global__ __launch_bounds__(128) void k_reduce(const float* __restrict__ P,
                                                float* __restrict__ AR,
                                                float* __restrict__ AI,
                                                float* __restrict__ sumsq,
                                                float scale) {
  int r = blockIdx.x, tile = blockIdx.y, c = threadIdx.x;
  float vR4[4] = {0.f, 0.f, 0.f, 0.f}, vI4[4] = {0.f, 0.f, 0.f, 0.f};
  for (int zz = 0; zz < ZSLABS; zz += 4) {
#pragma unroll
    for (int u = 0; u < 4; u++) {
      const float* base =
          P + ((size_t)(tile * ZSLABS + zz + u) * 2) * 16384 + r * 128 + c;
      vR4[u] += base[0];
      vI4[u] += base[16384];
    }
  }
  float vR = (vR4[0] + vR4[1]) + (vR4[2] + vR4[3]);
  float vI = (vI4[0] + vI4[1]) + (vI4[2] + vI4[3]);
  vR *= scale;
  vI *= scale;
  int i = (tile == 2) ? 128 + r : r;
  int j = (tile == 0) ? c : 128 + c;
  float ss = 0.f;
  bool diagTile = (tile != 1);
  if (!diagTile || c > r) {
    AR[i * 256 + j] = vR;
    AR[j * 256 + i] = vR;
    AI[i * 256 + j] = vI;
    AI[j * 256 + i] = -vI;
    ss = 2.f * (vR * vR + vI * vI);
  } else if (c == r) {
    AR[i * 256 + j] = vR;
    AI[i * 256 + j] = 0.f;
    ss = vR * vR;
  }
#pragma unroll
  for (int o = 32; o > 0; o >>= 1) ss += __shfl_down(ss, o);
  __shared__ float w2[2];
  if ((c & 63) == 0) w2[c >> 6] = ss;
  __syncthreads();
  if (c == 0) atomicAdd(sumsq, w2[0] + w2[1]);
}

// ---------------------------------------------------------------------------
// Newton-Schulz complex matmuls, 16x16 tile per block, interleaved re/im LDS.
// 4-way k-split accumulators: 8 independent FMA chains/thread -> throughput-
// bound even at 1 wave/SIMD (was a 512-long dependent chain, latency-bound).
// ---------------------------------------------------------------------------
__global__ __launch_bounds__(256) void k_csq(
    const float* __restrict__ XR, const float* __restrict__ XI,
    float* __restrict__ YR, float* __restrict__ YI,
    float* __restrict__ sumsqY, int accumNorm) {
  __shared__ float rp[16][256][2];
  __shared__ float cpT[16][258][2];
  int t = threadIdx.x;
  int bi = blockIdx.x >> 4, bj = blockIdx.x & 15;
#pragma unroll
  for (int q = 0; q < 16; q++) {
    rp[q][t][0] = XR[(bi * 16 + q) * 256 + t];
    rp[q][t][1] = XI[(bi * 16 + q) * 256 + t];
  }
  {
    const float* r0 = XR + t * 256 + bj * 16;
    const float* i0 = XI + t * 256 + bj * 16;
#pragma unroll
    for (int c = 0; c < 16; c++) {
      cpT[c][t][0] = r0[c];
      cpT[c][t][1] = i0[c];
    }
  }
  __syncthreads();
  int tx = t & 15, ty = t >> 4;
  float sR[4] = {0.f, 0.f, 0.f, 0.f}, sI[4] = {0.f, 0.f, 0.f, 0.f};
#pragma unroll 4
  for (int k0 = 0; k0 < 256; k0 += 4) {
#pragma unroll
    for (int u = 0; u < 4; u++) {
      float xr = rp[ty][k0 + u][0], xi = rp[ty][k0 + u][1];
      float yr = cpT[tx][k0 + u][0], yi = cpT[tx][k0 + u][1];
      sR[u] = fmaf(xr, yr, sR[u]);
      sR[u] = fmaf(-xi, yi, sR[u]);
      sI[u] = fmaf(xr, yi, sI[u]);
      sI[u] = fmaf(xi, yr, sI[u]);
    }
  }
  float fR = (sR[0] + sR[1]) + (sR[2] + sR[3]);
  float fI = (sI[0] + sI[1]) + (sI[2] + sI[3]);
  int i = bi * 16 + ty, j = bj * 16 + tx;
  YR[i * 256 + j] = fR;
  YI[i * 256 + j] = fI;
  if (accumNorm) {
    float v = fR * fR + fI * fI;
#pragma unroll
    for (int o = 32; o > 0; o >>= 1) v += __shfl_down(v, o);
    __shared__ float w4[4];
    if ((t & 63) == 0) w4[t >> 6] = v;
    __syncthreads();
    if (t == 0) atomicAdd(sumsqY, w4[0] + w4[1] + w4[2] + w4[3]);
  }
}

// Z = aC*X - bC*(X@Y).
// mode 0: first iter ON RAW A (norm-folding): f^2=scalars[0]=||A||_F^2,
//   ssqY=scalars[1]=||A^2||_F^2; Rhat=sqrt(2)*sqrt(ssqY)/f^2;
//   g=1/(1.75*Rhat); aC=1.5g/f, bC=0.5g^3/f^3  (== 1.5-NS on X0=A/f).
// mode 1: x <- 2x - x^3. mode 2: x <- 1.5x - 0.5x^3.
// finalTrace: instead of writing Z, accumulate out += -0.5*sum(A .* Z).
__global__ __launch_bounds__(256) void k_cupd(
    const float* __restrict__ XR, const float* __restrict__ XI,
    const float* __restrict__ YR, const float* __restrict__ YI,
    float* __restrict__ ZR, float* __restrict__ ZI,
    const float* __restrict__ scalars, int mode,
    const float* __restrict__ AR, const float* __restrict__ AI,
    float* __restrict__ out, int finalTrace) {
  __shared__ float rp[16][256][2];
  __shared__ float cpT[16][258][2];
  int t = threadIdx.x;
  int bi = blockIdx.x >> 4, bj = blockIdx.x & 15;
#pragma unroll
  for (int q = 0; q < 16; q++) {
    rp[q][t][0] = XR[(bi * 16 + q) * 256 + t];
    rp[q][t][1] = XI[(bi * 16 + q) * 256 + t];
  }
  {
    const float* r0 = YR + t * 256 + bj * 16;
    const float* i0 = YI + t * 256 + bj * 16;
#pragma unroll
    for (int c = 0; c < 16; c++) {
      cpT[c][t][0] = r0[c];
      cpT[c][t][1] = i0[c];
    }
  }
  __syncthreads();
  int tx = t & 15, ty = t >> 4;
  float sR[4] = {0.f, 0.f, 0.f, 0.f}, sI[4] = {0.f, 0.f, 0.f, 0.f};
#pragma unroll 4
  for (int k0 = 0; k0 < 256; k0 += 4) {
#pragma unroll
    for (int u = 0; u < 4; u++) {
      float xr = rp[ty][k0 + u][0], xi = rp[ty][k0 + u][1];
      float yr = cpT[tx][k0 + u][0], yi = cpT[tx][k0 + u][1];
      sR[u] = fmaf(xr, yr, sR[u]);
      sR[u] = fmaf(-xi, yi, sR[u]);
      sI[u] = fmaf(xr, yi, sI[u]);
      sI[u] = fmaf(xi, yr, sI[u]);
    }
  }
  float mR = (sR[0] + sR[1]) + (sR[2] + sR[3]);
  float mI = (sI[0] + sI[1]) + (sI[2] + sI[3]);
  float aC, bC;
  if (mode == 0) {
    float f2 = scalars[0];
    float f = sqrtf(f2);
    float Rhat = 1.41421356f * sqrtf(scalars[1]) / f2;
    float g = 1.0f / (1.75f * Rhat);
    aC = 1.5f * g / f;
    float gf = g / f;
    bC = 0.5f * gf * gf * gf;
  } else if (mode == 1) {
    aC = 2.0f;
    bC = 1.0f;
  } else {
    aC = 1.5f;
    bC = 0.5f;
  }
  int idx = (bi * 16 + ty) * 256 + bj * 16 + tx;
  float zr = aC * XR[idx] - bC * mR;
  float zi = aC * XI[idx] - bC * mI;
  if (!finalTrace) {
    ZR[idx] = zr;
    ZI[idx] = zi;
  } else {
    float v = AR[idx] * zr + AI[idx] * zi;
#pragma unroll
    for (int o = 32; o > 0; o >>= 1) v += __shfl_down(v, o);
    __shared__ float w4[4];
    if ((t & 63) == 0) w4[t >> 6] = v;
    __syncthreads();
    if (t == 0) atomicAdd(out, -0.5f * (w4[0] + w4[1] + w4[2] + w4[3]));
  }
}

// ---------------------------------------------------------------------------
extern "C" void kernel_launch(void* const* d_in, const int* in_sizes, int n_in,
                              void* d_out, int out_size, void* d_ws,
                              size_t ws_size, hipStream_t stream) {
  const float* x1 = (const float*)d_in[0];
  const float* x0 = (const float*)d_in[1];
  const float* W1 = (const float*)d_in[2];
  const float* b1 = (const float*)d_in[3];
  const float* W2 = (const float*)d_in[4];
  const float* b2 = (const float*)d_in[5];
  const float* W3 = (const float*)d_in[6];
  const float* b3 = (const float*)d_in[7];
  (void)n_in;
  (void)out_size;
  (void)ws_size;

  const int B = in_sizes[0] / 8;       // 65536
  const int total = 2 * B;             // 131072
  const int totalKb = total / 32;      // 4096
  const int kbPer = totalKb / ZSLABS;  // 16

  char* ws = (char*)d_ws;
  size_t off = 0;
  auto carve = [&](size_t bytes) -> void* {
    off = (off + 255) & ~(size_t)255;
    void* p = ws + off;
    off += bytes;
    return p;
  };
  float* hz = (float*)carve((size_t)total * 16 * 4);              // 8.4 MB
  _Float16* Ach = (_Float16*)carve((size_t)totalKb * 16384 * 2);  // 134 MB
  float* P = (float*)carve((size_t)3 * ZSLABS * 2 * 16384 * 4);   // 100.7 MB
  float* scalars = (float*)carve(256);  // [0]=sumsq(A), [1]=sumsq(A^2)
  float* AR = (float*)carve(256 * 256 * 4);
  float* AI = (float*)carve(256 * 256 * 4);
  float* XR = (float*)carve(256 * 256 * 4);
  float* XI = (float*)carve(256 * 256 * 4);
  float* YR = (float*)carve(256 * 256 * 4);
  float* YI = (float*)carve(256 * 256 * 4);
  float* ZR = (float*)carve(256 * 256 * 4);
  float* ZI = (float*)carve(256 * 256 * 4);

  k_mlp<<<(total + 255) / 256, 256, 0, stream>>>(
      x1, x0, W1, b1, W2, b2, W3, b3, hz, B, scalars, (float*)d_out);
  k_gen<<<totalKb, 256, 0, stream>>>(hz, Ach);
  k_gemm_t<1><<<dim3(2, ZSLABS), 256, 0, stream>>>(Ach, P, kbPer);
  k_gemm_t<2><<<dim3(1, ZSLABS), 256, 0, stream>>>(Ach, P, kbPer);
  k_reduce<<<dim3(128, 3), 128, 0, stream>>>(P, AR, AI, scalars,
                                             1.0f / (256.0f * (float)B));

  // NS schedule (PROVEN in R3, absmax=0.0 — do not shorten; spectrum has a
  // near-zero eigenvalue cluster that shallow schedules truncate):
  // 1x clamp(1.5-NS, rescaled, on raw A via norm-folding)
  // + 7x (2x - x^3) + 6x (1.5-NS); trace fused into the last update.
  const int NIT = 14;
  float *cR = AR, *cI = AI, *nR = XR, *nI = XI;
  for (int it = 0; it < NIT; it++) {
    int mode = (it == 0) ? 0 : (it <= 7 ? 1 : 2);
    int fin = (it == NIT - 1) ? 1 : 0;
    k_csq<<<256, 256, 0, stream>>>(cR, cI, YR, YI, scalars + 1, it == 0);
    k_cupd<<<256, 256, 0, stream>>>(cR, cI, YR, YI, nR, nI, scalars, mode, AR,
                                    AI, (float*)d_out, fin);
    if (it == 0) {
      cR = XR; cI = XI; nR = ZR; nI = ZI;
    } else {
      std::swap(cR, nR);
      std::swap(cI, nI);
    }
  }
}

// Round 8
// 310.244 us; speedup vs baseline: 1.1737x; 1.1737x over previous
//
#include <hip/hip_runtime.h>
#include <cstdint>
#include <cstddef>
#include <utility>

#define PI_F 3.14159265358979323846f

typedef __attribute__((ext_vector_type(8))) _Float16 half8;
typedef __attribute__((ext_vector_type(4))) float f32x4;

struct U4 { unsigned int w[4]; };

static __device__ __forceinline__ unsigned int packhalf2(float c, float s) {
  _Float16 hc = (_Float16)c, hs = (_Float16)s;
  unsigned short uc = __builtin_bit_cast(unsigned short, hc);
  unsigned short us = __builtin_bit_cast(unsigned short, hs);
  return (unsigned int)uc | ((unsigned int)us << 16);
}

static __device__ __forceinline__ void load16_lds(const void* g, void* l) {
  __builtin_amdgcn_global_load_lds(
      (const __attribute__((address_space(1))) unsigned int*)g,
      (__attribute__((address_space(3))) unsigned int*)l, 16, 0, 0);
}

// ---------------------------------------------------------------------------
// K1: MLP for all 2B samples -> hz[sample][16] = {h[0..7], z[0..6], 0}.
// Block 0 thread 0 also zero-inits scalars + out (replaces memset dispatches).
// ---------------------------------------------------------------------------
__global__ __launch_bounds__(256) void k_mlp(
    const float* __restrict__ x1, const float* __restrict__ x0,
    const float* __restrict__ W1, const float* __restrict__ b1,
    const float* __restrict__ W2, const float* __restrict__ b2,
    const float* __restrict__ W3, const float* __restrict__ b3,
    float* __restrict__ hz, int B, float* __restrict__ scalars,
    float* __restrict__ out) {
  int s = blockIdx.x * blockDim.x + threadIdx.x;
  if (blockIdx.x == 0 && threadIdx.x == 0) {
    scalars[0] = 0.f;
    scalars[1] = 0.f;
    out[0] = 0.f;
  }
  if (s >= 2 * B) return;
  const float* xp = (s < B) ? (x1 + (size_t)s * 8) : (x0 + (size_t)(s - B) * 8);
  float x[8];
#pragma unroll
  for (int k = 0; k < 8; k++) x[k] = xp[k];
  float a1[10];
#pragma unroll
  for (int o = 0; o < 10; o++) {
    float v = b1[o];
#pragma unroll
    for (int k = 0; k < 8; k++) v = fmaf(W1[o * 8 + k], x[k], v);
    a1[o] = fmaxf(v, 0.f);
  }
  float a2[10];
#pragma unroll
  for (int o = 0; o < 10; o++) {
    float v = b2[o];
#pragma unroll
    for (int k = 0; k < 10; k++) v = fmaf(W2[o * 10 + k], a1[k], v);
    a2[o] = fmaxf(v, 0.f);
  }
  float h[8];
#pragma unroll
  for (int o = 0; o < 8; o++) {
    float v = b3[o];
#pragma unroll
    for (int k = 0; k < 10; k++) v = fmaf(W3[o * 10 + k], a2[k], v);
    h[o] = v;
  }
  float outv[16];
#pragma unroll
  for (int k = 0; k < 8; k++) outv[k] = h[k];
#pragma unroll
  for (int k = 0; k < 7; k++) outv[8 + k] = (PI_F - h[k]) * (PI_F - h[k + 1]);
  outv[15] = 0.f;
  float4* dst = (float4*)(hz + (size_t)s * 16);
#pragma unroll
  for (int q = 0; q < 4; q++) dst[q] = ((float4*)outv)[q];
}

// ---------------------------------------------------------------------------
// K2: generate fp16 (cos,sin) pairs. A layout: [kb][256 rows][64 halfs],
// rows are 128B; within a row the 16B chunks are XOR-swizzled by (row&7):
//   physical_half(row, logical_half L) = L ^ ((row&7)<<3)
// Gray-code walk (one sign flip per row) + HW v_sin/v_cos in revolutions.
// ---------------------------------------------------------------------------
__global__ __launch_bounds__(256) void k_gen(const float* __restrict__ hz,
                                             _Float16* __restrict__ Ach) {
  __shared__ float hzl[32][17];  // padded: conflict-free column reads
  int kb = blockIdx.x, t = threadIdx.x;
  if (t < 128) {
    int smp = t >> 2, q = t & 3;
    const float4 v =
        *(const float4*)(hz + (size_t)(kb * 32 + smp) * 16 + q * 4);
    hzl[smp][q * 4 + 0] = v.x;
    hzl[smp][q * 4 + 1] = v.y;
    hzl[smp][q * 4 + 2] = v.z;
    hzl[smp][q * 4 + 3] = v.w;
  }
  __syncthreads();
  int s = t & 31, oct = t >> 5;  // sample-in-block, basis octet (wires 5-7)
  float h[8], z[7];
#pragma unroll
  for (int k = 0; k < 8; k++) h[k] = hzl[s][k];
#pragma unroll
  for (int k = 0; k < 7; k++) z[k] = hzl[s][8 + k];
  float S5 = (oct & 4) ? -1.f : 1.f;
  float S6 = (oct & 2) ? -1.f : 1.f;
  float S7 = (oct & 1) ? -1.f : 1.f;
  float sg[5] = {1.f, 1.f, 1.f, 1.f, 1.f};
  float phi = h[0] + h[1] + h[2] + h[3] + h[4] + S5 * h[5] + S6 * h[6] +
              S7 * h[7] + z[0] + z[1] + z[2] + z[3] + S5 * z[4] +
              S5 * S6 * z[5] + S6 * S7 * z[6];
  _Float16* dst = Ach + (size_t)kb * 16384;
  const int halfoff = (2 * s) ^ (oct << 3);

  auto emit = [&](int g, float ph) {
    float r = ph * 0.07957747154594767f;  // ph/(4*pi) revolutions
    r = r - floorf(r);
    float sv = __builtin_amdgcn_sinf(r);
    float cv = __builtin_amdgcn_cosf(r);
    *(unsigned int*)(dst + (size_t)(g * 8 + oct) * 64 + halfoff) =
        packhalf2(cv, sv);
  };

  emit(0, phi);
#pragma unroll
  for (int jj = 1; jj < 32; ++jj) {
    const int b = __builtin_ctz(jj);
    const int w = 4 - b;
    float nbl = (w == 0) ? 0.f : sg[w - 1] * z[w - 1];
    float nbr = (w == 4) ? S5 * z[4] : sg[w + 1] * z[w];
    phi -= 2.f * sg[w] * (h[w] + nbl + nbr);
    sg[w] = -sg[w];
    emit(jj ^ (jj >> 1), phi);
  }
}

// ---------------------------------------------------------------------------
// K3: unified triangular split-K MFMA GEMM -> per-slab partial tiles.
// grid (3, ZSLABS): bx 0 -> tile0 (0,0) diag; bx 1 -> tile2 (128,128) diag;
// bx 2 -> tile1 (0,128) off-diag. Diag blocks stage one panel only.
// Partials P[(tile*ZSLABS+z)*2 + plane][128*128] f32.
// ---------------------------------------------------------------------------
#define ZSLABS 256

__global__ __launch_bounds__(256) void k_gemm(const _Float16* __restrict__ A,
                                              float* __restrict__ P,
                                              int kbPer) {
  __shared__ _Float16 lds[2][2][128][64];
  int bx = blockIdx.x, z = blockIdx.y;
  bool diag = (bx < 2);
  int mbase = (bx == 2) ? 0 : bx * 128;
  int nbase = (bx == 0) ? 0 : 128;
  int tile = (bx == 2) ? 1 : bx * 2;
  int bp = diag ? 0 : 1;  // B panel index
  int t = threadIdx.x, wave = t >> 6, lane = t & 63;
  int wm = wave >> 1, wn = wave & 1;
  unsigned int reMask = (z < ZSLABS / 2) ? 0u : 0x80008000u;
  unsigned int imMask = (z < ZSLABS / 2) ? 0x80000000u : 0x00008000u;
  int kb0 = z * kbPer;

  auto stage = [&](int it, int buf) {
    size_t kb = (size_t)(kb0 + it);
    const char* gA = (const char*)A + kb * 32768 + (size_t)mbase * 128;
    char* lA = (char*)&lds[buf][0][0][0];
#pragma unroll
    for (int q = 0; q < 4; q++) {
      int woff = wave * 4096 + q * 1024;
      load16_lds(gA + woff + lane * 16, lA + woff);
    }
    if (!diag) {
      const char* gB = (const char*)A + kb * 32768 + (size_t)nbase * 128;
      char* lB = (char*)&lds[buf][1][0][0];
#pragma unroll
      for (int q = 0; q < 4; q++) {
        int woff = wave * 4096 + q * 1024;
        load16_lds(gB + woff + lane * 16, lB + woff);
      }
    }
  };

  f32x4 accR[4][4] = {};
  f32x4 accI[4][4] = {};
  stage(0, 0);
  for (int it = 0; it < kbPer; ++it) {
    __syncthreads();
    if (it + 1 < kbPer) stage(it + 1, (it + 1) & 1);
    int buf = it & 1;
#pragma unroll
    for (int kk = 0; kk < 2; kk++) {
      int cbase = kk * 4 + (lane >> 4);
      half8 af[4], bfr[4], bfi[4];
#pragma unroll
      for (int fm = 0; fm < 4; fm++) {
        int r = wm * 64 + fm * 16 + (lane & 15);
        af[fm] = *(const half8*)&lds[buf][0][r][(cbase ^ (r & 7)) << 3];
      }
#pragma unroll
      for (int fn = 0; fn < 4; fn++) {
        int r = wn * 64 + fn * 16 + (lane & 15);
        half8 bv = *(const half8*)&lds[buf][bp][r][(cbase ^ (r & 7)) << 3];
        U4 u = __builtin_bit_cast(U4, bv), ur, ui;
#pragma unroll
        for (int q = 0; q < 4; q++) {
          unsigned int xv = u.w[q];
          ur.w[q] = xv ^ reMask;
          ui.w[q] = ((xv << 16) | (xv >> 16)) ^ imMask;
        }
        bfr[fn] = __builtin_bit_cast(half8, ur);
        bfi[fn] = __builtin_bit_cast(half8, ui);
      }
#pragma unroll
      for (int fm = 0; fm < 4; fm++)
#pragma unroll
        for (int fn = 0; fn < 4; fn++) {
          accR[fm][fn] = __builtin_amdgcn_mfma_f32_16x16x32_f16(
              af[fm], bfr[fn], accR[fm][fn], 0, 0, 0);
          accI[fm][fn] = __builtin_amdgcn_mfma_f32_16x16x32_f16(
              af[fm], bfi[fn], accI[fm][fn], 0, 0, 0);
        }
    }
  }
  float* PR = P + ((size_t)(tile * ZSLABS + z) * 2) * 16384;
  float* PI = PR + 16384;
  int r4 = (lane >> 4) * 4, cj = lane & 15;
#pragma unroll
  for (int fm = 0; fm < 4; fm++)
#pragma unroll
    for (int fn = 0; fn < 4; fn++)
#pragma unroll
      for (int r = 0; r < 4; r++) {
        int li = wm * 64 + fm * 16 + r4 + r;
        int lj = wn * 64 + fn * 16 + cj;
        PR[li * 128 + lj] = accR[fm][fn][r];
        PI[li * 128 + lj] = accI[fm][fn][r];
      }
}

// ---------------------------------------------------------------------------
// K4a: stage-1 reduce: grid (128 rows, 3 tiles, 8 groups), 128 threads.
// Each block sums 32 slabs for one (tile,row); 24 waves/CU -> HBM-bound.
// Q layout: QR at ((g*3+tile)*128+r)*128+c ; QI at +8*3*16384.
// ---------------------------------------------------------------------------
__global__ __launch_bounds__(128) void k_reduce1(const float* __restrict__ P,
                                                 float* __restrict__ Q) {
  int r = blockIdx.x, tile = blockIdx.y, g = blockIdx.z, c = threadIdx.x;
  const float* base =
      P + ((size_t)(tile * ZSLABS + g * 32) * 2) * 16384 + r * 128 + c;
  float vR = 0.f, vI = 0.f;
  for (int u = 0; u < 32; u++) {
    vR += base[(size_t)u * 32768];
    vI += base[(size_t)u * 32768 + 16384];
  }
  size_t qidx = ((size_t)(g * 3 + tile) * 128 + r) * 128 + c;
  Q[qidx] = vR;
  Q[qidx + (size_t)8 * 3 * 16384] = vI;
}

// K4b: stage-2: sum 8 groups, hermitize -> A, accumulate ||A||_F^2.
__global__ __launch_bounds__(128) void k_reduce2(const float* __restrict__ Q,
                                                 float* __restrict__ AR,
                                                 float* __restrict__ AI,
                                                 float* __restrict__ sumsq,
                                                 float scale) {
  int r = blockIdx.x, tile = blockIdx.y, c = threadIdx.x;
  float vR = 0.f, vI = 0.f;
#pragma unroll
  for (int g = 0; g < 8; g++) {
    size_t qidx = ((size_t)(g * 3 + tile) * 128 + r) * 128 + c;
    vR += Q[qidx];
    vI += Q[qidx + (size_t)8 * 3 * 16384];
  }
  vR *= scale;
  vI *= scale;
  int i = (tile == 2) ? 128 + r : r;
  int j = (tile == 0) ? c : 128 + c;
  float ss = 0.f;
  bool diagTile = (tile != 1);
  if (!diagTile || c > r) {
    AR[i * 256 + j] = vR;
    AR[j * 256 + i] = vR;
    AI[i * 256 + j] = vI;
    AI[j * 256 + i] = -vI;
    ss = 2.f * (vR * vR + vI * vI);
  } else if (c == r) {
    AR[i * 256 + j] = vR;
    AI[i * 256 + j] = 0.f;
    ss = vR * vR;
  }
#pragma unroll
  for (int o = 32; o > 0; o >>= 1) ss += __shfl_down(ss, o);
  __shared__ float w2[2];
  if ((c & 63) == 0) w2[c >> 6] = ss;
  __syncthreads();
  if (c == 0) atomicAdd(sumsq, w2[0] + w2[1]);
}

// ---------------------------------------------------------------------------
// Newton-Schulz complex matmuls (R6-proven inner loop — do not restructure:
// the 4-way k-split variant regressed ~1 us/kernel, R7 post-mortem).
// ---------------------------------------------------------------------------
__global__ __launch_bounds__(256) void k_csq(
    const float* __restrict__ XR, const float* __restrict__ XI,
    float* __restrict__ YR, float* __restrict__ YI,
    float* __restrict__ sumsqY, int accumNorm) {
  __shared__ float rp[16][256][2];
  __shared__ float cpT[16][258][2];
  int t = threadIdx.x;
  int bi = blockIdx.x >> 4, bj = blockIdx.x & 15;
#pragma unroll
  for (int q = 0; q < 16; q++) {
    rp[q][t][0] = XR[(bi * 16 + q) * 256 + t];
    rp[q][t][1] = XI[(bi * 16 + q) * 256 + t];
  }
  {
    const float* r0 = XR + t * 256 + bj * 16;
    const float* i0 = XI + t * 256 + bj * 16;
#pragma unroll
    for (int c = 0; c < 16; c++) {
      cpT[c][t][0] = r0[c];
      cpT[c][t][1] = i0[c];
    }
  }
  __syncthreads();
  int tx = t & 15, ty = t >> 4;
  float sR = 0.f, sI = 0.f;
#pragma unroll 8
  for (int k = 0; k < 256; k++) {
    float xr = rp[ty][k][0], xi = rp[ty][k][1];
    float yr = cpT[tx][k][0], yi = cpT[tx][k][1];
    sR = fmaf(xr, yr, sR);
    sR = fmaf(-xi, yi, sR);
    sI = fmaf(xr, yi, sI);
    sI = fmaf(xi, yr, sI);
  }
  int i = bi * 16 + ty, j = bj * 16 + tx;
  YR[i * 256 + j] = sR;
  YI[i * 256 + j] = sI;
  if (accumNorm) {
    float v = sR * sR + sI * sI;
#pragma unroll
    for (int o = 32; o > 0; o >>= 1) v += __shfl_down(v, o);
    __shared__ float w4[4];
    if ((t & 63) == 0) w4[t >> 6] = v;
    __syncthreads();
    if (t == 0) atomicAdd(sumsqY, w4[0] + w4[1] + w4[2] + w4[3]);
  }
}

// Z = aC*X - bC*(X@Y).
// mode 0: first iter ON RAW A (norm-folding): f^2=scalars[0]=||A||_F^2,
//   ssqY=scalars[1]=||A^2||_F^2; Rhat=sqrt(2)*sqrt(ssqY)/f^2;
//   g=1/(1.75*Rhat); aC=1.5g/f, bC=0.5(g/f)^3  (== 1.5-NS on X0=A/f).
// mode 1: x <- 2x - x^3. mode 2: x <- 1.5x - 0.5x^3.
// finalTrace: instead of writing Z, accumulate out += -0.5*sum(A .* Z).
__global__ __launch_bounds__(256) void k_cupd(
    const float* __restrict__ XR, const float* __restrict__ XI,
    const float* __restrict__ YR, const float* __restrict__ YI,
    float* __restrict__ ZR, float* __restrict__ ZI,
    const float* __restrict__ scalars, int mode,
    const float* __restrict__ AR, const float* __restrict__ AI,
    float* __restrict__ out, int finalTrace) {
  __shared__ float rp[16][256][2];
  __shared__ float cpT[16][258][2];
  int t = threadIdx.x;
  int bi = blockIdx.x >> 4, bj = blockIdx.x & 15;
#pragma unroll
  for (int q = 0; q < 16; q++) {
    rp[q][t][0] = XR[(bi * 16 + q) * 256 + t];
    rp[q][t][1] = XI[(bi * 16 + q) * 256 + t];
  }
  {
    const float* r0 = YR + t * 256 + bj * 16;
    const float* i0 = YI + t * 256 + bj * 16;
#pragma unroll
    for (int c = 0; c < 16; c++) {
      cpT[c][t][0] = r0[c];
      cpT[c][t][1] = i0[c];
    }
  }
  __syncthreads();
  int tx = t & 15, ty = t >> 4;
  float sR = 0.f, sI = 0.f;
#pragma unroll 8
  for (int k = 0; k < 256; k++) {
    float xr = rp[ty][k][0], xi = rp[ty][k][1];
    float yr = cpT[tx][k][0], yi = cpT[tx][k][1];
    sR = fmaf(xr, yr, sR);
    sR = fmaf(-xi, yi, sR);
    sI = fmaf(xr, yi, sI);
    sI = fmaf(xi, yr, sI);
  }
  float aC, bC;
  if (mode == 0) {
    float f2 = scalars[0];
    float f = sqrtf(f2);
    float Rhat = 1.41421356f * sqrtf(scalars[1]) / f2;
    float g = 1.0f / (1.75f * Rhat);
    aC = 1.5f * g / f;
    float gf = g / f;
    bC = 0.5f * gf * gf * gf;
  } else if (mode == 1) {
    aC = 2.0f;
    bC = 1.0f;
  } else {
    aC = 1.5f;
    bC = 0.5f;
  }
  int idx = (bi * 16 + ty) * 256 + bj * 16 + tx;
  float zr = aC * XR[idx] - bC * sR;
  float zi = aC * XI[idx] - bC * sI;
  if (!finalTrace) {
    ZR[idx] = zr;
    ZI[idx] = zi;
  } else {
    float v = AR[idx] * zr + AI[idx] * zi;
#pragma unroll
    for (int o = 32; o > 0; o >>= 1) v += __shfl_down(v, o);
    __shared__ float w4[4];
    if ((t & 63) == 0) w4[t >> 6] = v;
    __syncthreads();
    if (t == 0) atomicAdd(out, -0.5f * (w4[0] + w4[1] + w4[2] + w4[3]));
  }
}

// ---------------------------------------------------------------------------
extern "C" void kernel_launch(void* const* d_in, const int* in_sizes, int n_in,
                              void* d_out, int out_size, void* d_ws,
                              size_t ws_size, hipStream_t stream) {
  const float* x1 = (const float*)d_in[0];
  const float* x0 = (const float*)d_in[1];
  const float* W1 = (const float*)d_in[2];
  const float* b1 = (const float*)d_in[3];
  const float* W2 = (const float*)d_in[4];
  const float* b2 = (const float*)d_in[5];
  const float* W3 = (const float*)d_in[6];
  const float* b3 = (const float*)d_in[7];
  (void)n_in;
  (void)out_size;
  (void)ws_size;

  const int B = in_sizes[0] / 8;       // 65536
  const int total = 2 * B;             // 131072
  const int totalKb = total / 32;      // 4096
  const int kbPer = totalKb / ZSLABS;  // 16

  char* ws = (char*)d_ws;
  size_t off = 0;
  auto carve = [&](size_t bytes) -> void* {
    off = (off + 255) & ~(size_t)255;
    void* p = ws + off;
    off += bytes;
    return p;
  };
  float* hz = (float*)carve((size_t)total * 16 * 4);              // 8.4 MB
  _Float16* Ach = (_Float16*)carve((size_t)totalKb * 16384 * 2);  // 134 MB
  float* P = (float*)carve((size_t)3 * ZSLABS * 2 * 16384 * 4);   // 100.7 MB
  float* Q = (float*)carve((size_t)2 * 8 * 3 * 16384 * 4);        // 3.1 MB
  float* scalars = (float*)carve(256);  // [0]=sumsq(A), [1]=sumsq(A^2)
  float* AR = (float*)carve(256 * 256 * 4);
  float* AI = (float*)carve(256 * 256 * 4);
  float* XR = (float*)carve(256 * 256 * 4);
  float* XI = (float*)carve(256 * 256 * 4);
  float* YR = (float*)carve(256 * 256 * 4);
  float* YI = (float*)carve(256 * 256 * 4);
  float* ZR = (float*)carve(256 * 256 * 4);
  float* ZI = (float*)carve(256 * 256 * 4);

  k_mlp<<<(total + 255) / 256, 256, 0, stream>>>(
      x1, x0, W1, b1, W2, b2, W3, b3, hz, B, scalars, (float*)d_out);
  k_gen<<<totalKb, 256, 0, stream>>>(hz, Ach);
  k_gemm<<<dim3(3, ZSLABS), 256, 0, stream>>>(Ach, P, kbPer);
  k_reduce1<<<dim3(128, 3, 8), 128, 0, stream>>>(P, Q);
  k_reduce2<<<dim3(128, 3), 128, 0, stream>>>(Q, AR, AI, scalars,
                                              1.0f / (256.0f * (float)B));

  // NS schedule: 1x clamp(1.5-NS, rescaled, raw-A norm-folded)
  // + 7x (2x - x^3) + 5x (1.5-NS); trace fused into the last update.
  // Depth calibrated on R2 (M=50 -> 8.5e-4) and R4 (M=69 -> 6.1e-4):
  // M=555 here -> residual <= ~4e-5, >=8x margin. Doubling phase untouched.
  const int NIT = 13;
  float *cR = AR, *cI = AI, *nR = XR, *nI = XI;
  for (int it = 0; it < NIT; it++) {
    int mode = (it == 0) ? 0 : (it <= 7 ? 1 : 2);
    int fin = (it == NIT - 1) ? 1 : 0;
    k_csq<<<256, 256, 0, stream>>>(cR, cI, YR, YI, scalars + 1, it == 0);
    k_cupd<<<256, 256, 0, stream>>>(cR, cI, YR, YI, nR, nI, scalars, mode, AR,
                                    AI, (float*)d_out, fin);
    if (it == 0) {
      cR = XR; cI = XI; nR = ZR; nI = ZI;
    } else {
      std::swap(cR, nR);
      std::swap(cI, nI);
    }
  }
}

// Round 9
// 264.805 us; speedup vs baseline: 1.3751x; 1.1716x over previous
//
#include <hip/hip_runtime.h>
#include <cstdint>
#include <cstddef>
#include <utility>

#define PI_F 3.14159265358979323846f

typedef __attribute__((ext_vector_type(8))) _Float16 half8;
typedef __attribute__((ext_vector_type(4))) float f32x4;

struct U4 { unsigned int w[4]; };

static __device__ __forceinline__ unsigned int packhalf2(float c, float s) {
  _Float16 hc = (_Float16)c, hs = (_Float16)s;
  unsigned short uc = __builtin_bit_cast(unsigned short, hc);
  unsigned short us = __builtin_bit_cast(unsigned short, hs);
  return (unsigned int)uc | ((unsigned int)us << 16);
}

static __device__ __forceinline__ void load16_lds(const void* g, void* l) {
  __builtin_amdgcn_global_load_lds(
      (const __attribute__((address_space(1))) unsigned int*)g,
      (__attribute__((address_space(3))) unsigned int*)l, 16, 0, 0);
}

// ---------------------------------------------------------------------------
// K1: MLP for all 2B samples -> hz[sample][16] = {h[0..7], z[0..6], 0}.
// Block 0 thread 0 also zero-inits scalars + out (replaces memset dispatches).
// ---------------------------------------------------------------------------
__global__ __launch_bounds__(256) void k_mlp(
    const float* __restrict__ x1, const float* __restrict__ x0,
    const float* __restrict__ W1, const float* __restrict__ b1,
    const float* __restrict__ W2, const float* __restrict__ b2,
    const float* __restrict__ W3, const float* __restrict__ b3,
    float* __restrict__ hz, int B, float* __restrict__ scalars,
    float* __restrict__ out) {
  int s = blockIdx.x * blockDim.x + threadIdx.x;
  if (blockIdx.x == 0 && threadIdx.x == 0) {
    scalars[0] = 0.f;
    scalars[1] = 0.f;
    out[0] = 0.f;
  }
  if (s >= 2 * B) return;
  const float* xp = (s < B) ? (x1 + (size_t)s * 8) : (x0 + (size_t)(s - B) * 8);
  float x[8];
#pragma unroll
  for (int k = 0; k < 8; k++) x[k] = xp[k];
  float a1[10];
#pragma unroll
  for (int o = 0; o < 10; o++) {
    float v = b1[o];
#pragma unroll
    for (int k = 0; k < 8; k++) v = fmaf(W1[o * 8 + k], x[k], v);
    a1[o] = fmaxf(v, 0.f);
  }
  float a2[10];
#pragma unroll
  for (int o = 0; o < 10; o++) {
    float v = b2[o];
#pragma unroll
    for (int k = 0; k < 10; k++) v = fmaf(W2[o * 10 + k], a1[k], v);
    a2[o] = fmaxf(v, 0.f);
  }
  float h[8];
#pragma unroll
  for (int o = 0; o < 8; o++) {
    float v = b3[o];
#pragma unroll
    for (int k = 0; k < 10; k++) v = fmaf(W3[o * 10 + k], a2[k], v);
    h[o] = v;
  }
  float outv[16];
#pragma unroll
  for (int k = 0; k < 8; k++) outv[k] = h[k];
#pragma unroll
  for (int k = 0; k < 7; k++) outv[8 + k] = (PI_F - h[k]) * (PI_F - h[k + 1]);
  outv[15] = 0.f;
  float4* dst = (float4*)(hz + (size_t)s * 16);
#pragma unroll
  for (int q = 0; q < 4; q++) dst[q] = ((float4*)outv)[q];
}

// ---------------------------------------------------------------------------
// K2: generate fp16 (cos,sin) pairs. A layout: [kb][256 rows][64 halfs],
// rows are 128B; within a row the 16B chunks are XOR-swizzled by (row&7):
//   physical_half(row, logical_half L) = L ^ ((row&7)<<3)
// Gray-code walk (one sign flip per row) + HW v_sin/v_cos in revolutions.
// ---------------------------------------------------------------------------
__global__ __launch_bounds__(256) void k_gen(const float* __restrict__ hz,
                                             _Float16* __restrict__ Ach) {
  __shared__ float hzl[32][17];  // padded: conflict-free column reads
  int kb = blockIdx.x, t = threadIdx.x;
  if (t < 128) {
    int smp = t >> 2, q = t & 3;
    const float4 v =
        *(const float4*)(hz + (size_t)(kb * 32 + smp) * 16 + q * 4);
    hzl[smp][q * 4 + 0] = v.x;
    hzl[smp][q * 4 + 1] = v.y;
    hzl[smp][q * 4 + 2] = v.z;
    hzl[smp][q * 4 + 3] = v.w;
  }
  __syncthreads();
  int s = t & 31, oct = t >> 5;  // sample-in-block, basis octet (wires 5-7)
  float h[8], z[7];
#pragma unroll
  for (int k = 0; k < 8; k++) h[k] = hzl[s][k];
#pragma unroll
  for (int k = 0; k < 7; k++) z[k] = hzl[s][8 + k];
  float S5 = (oct & 4) ? -1.f : 1.f;
  float S6 = (oct & 2) ? -1.f : 1.f;
  float S7 = (oct & 1) ? -1.f : 1.f;
  float sg[5] = {1.f, 1.f, 1.f, 1.f, 1.f};
  float phi = h[0] + h[1] + h[2] + h[3] + h[4] + S5 * h[5] + S6 * h[6] +
              S7 * h[7] + z[0] + z[1] + z[2] + z[3] + S5 * z[4] +
              S5 * S6 * z[5] + S6 * S7 * z[6];
  _Float16* dst = Ach + (size_t)kb * 16384;
  const int halfoff = (2 * s) ^ (oct << 3);

  auto emit = [&](int g, float ph) {
    float r = ph * 0.07957747154594767f;  // ph/(4*pi) revolutions
    r = r - floorf(r);
    float sv = __builtin_amdgcn_sinf(r);
    float cv = __builtin_amdgcn_cosf(r);
    *(unsigned int*)(dst + (size_t)(g * 8 + oct) * 64 + halfoff) =
        packhalf2(cv, sv);
  };

  emit(0, phi);
#pragma unroll
  for (int jj = 1; jj < 32; ++jj) {
    const int b = __builtin_ctz(jj);
    const int w = 4 - b;
    float nbl = (w == 0) ? 0.f : sg[w - 1] * z[w - 1];
    float nbr = (w == 4) ? S5 * z[4] : sg[w + 1] * z[w];
    phi -= 2.f * sg[w] * (h[w] + nbl + nbr);
    sg[w] = -sg[w];
    emit(jj ^ (jj >> 1), phi);
  }
}

// ---------------------------------------------------------------------------
// K3: unified triangular split-K MFMA GEMM -> per-slab partial tiles.
// grid (3, ZSLABS): bx 0 -> tile0 (0,0) diag; bx 1 -> tile2 (128,128) diag;
// bx 2 -> tile1 (0,128) off-diag. Diag blocks stage one panel only.
// ---------------------------------------------------------------------------
#define ZSLABS 256

__global__ __launch_bounds__(256) void k_gemm(const _Float16* __restrict__ A,
                                              float* __restrict__ P,
                                              int kbPer) {
  __shared__ _Float16 lds[2][2][128][64];
  int bx = blockIdx.x, z = blockIdx.y;
  bool diag = (bx < 2);
  int mbase = (bx == 2) ? 0 : bx * 128;
  int nbase = (bx == 0) ? 0 : 128;
  int tile = (bx == 2) ? 1 : bx * 2;
  int bp = diag ? 0 : 1;  // B panel index
  int t = threadIdx.x, wave = t >> 6, lane = t & 63;
  int wm = wave >> 1, wn = wave & 1;
  unsigned int reMask = (z < ZSLABS / 2) ? 0u : 0x80008000u;
  unsigned int imMask = (z < ZSLABS / 2) ? 0x80000000u : 0x00008000u;
  int kb0 = z * kbPer;

  auto stage = [&](int it, int buf) {
    size_t kb = (size_t)(kb0 + it);
    const char* gA = (const char*)A + kb * 32768 + (size_t)mbase * 128;
    char* lA = (char*)&lds[buf][0][0][0];
#pragma unroll
    for (int q = 0; q < 4; q++) {
      int woff = wave * 4096 + q * 1024;
      load16_lds(gA + woff + lane * 16, lA + woff);
    }
    if (!diag) {
      const char* gB = (const char*)A + kb * 32768 + (size_t)nbase * 128;
      char* lB = (char*)&lds[buf][1][0][0];
#pragma unroll
      for (int q = 0; q < 4; q++) {
        int woff = wave * 4096 + q * 1024;
        load16_lds(gB + woff + lane * 16, lB + woff);
      }
    }
  };

  f32x4 accR[4][4] = {};
  f32x4 accI[4][4] = {};
  stage(0, 0);
  for (int it = 0; it < kbPer; ++it) {
    __syncthreads();
    if (it + 1 < kbPer) stage(it + 1, (it + 1) & 1);
    int buf = it & 1;
#pragma unroll
    for (int kk = 0; kk < 2; kk++) {
      int cbase = kk * 4 + (lane >> 4);
      half8 af[4], bfr[4], bfi[4];
#pragma unroll
      for (int fm = 0; fm < 4; fm++) {
        int r = wm * 64 + fm * 16 + (lane & 15);
        af[fm] = *(const half8*)&lds[buf][0][r][(cbase ^ (r & 7)) << 3];
      }
#pragma unroll
      for (int fn = 0; fn < 4; fn++) {
        int r = wn * 64 + fn * 16 + (lane & 15);
        half8 bv = *(const half8*)&lds[buf][bp][r][(cbase ^ (r & 7)) << 3];
        U4 u = __builtin_bit_cast(U4, bv), ur, ui;
#pragma unroll
        for (int q = 0; q < 4; q++) {
          unsigned int xv = u.w[q];
          ur.w[q] = xv ^ reMask;
          ui.w[q] = ((xv << 16) | (xv >> 16)) ^ imMask;
        }
        bfr[fn] = __builtin_bit_cast(half8, ur);
        bfi[fn] = __builtin_bit_cast(half8, ui);
      }
#pragma unroll
      for (int fm = 0; fm < 4; fm++)
#pragma unroll
        for (int fn = 0; fn < 4; fn++) {
          accR[fm][fn] = __builtin_amdgcn_mfma_f32_16x16x32_f16(
              af[fm], bfr[fn], accR[fm][fn], 0, 0, 0);
          accI[fm][fn] = __builtin_amdgcn_mfma_f32_16x16x32_f16(
              af[fm], bfi[fn], accI[fm][fn], 0, 0, 0);
        }
    }
  }
  float* PR = P + ((size_t)(tile * ZSLABS + z) * 2) * 16384;
  float* PI = PR + 16384;
  int r4 = (lane >> 4) * 4, cj = lane & 15;
#pragma unroll
  for (int fm = 0; fm < 4; fm++)
#pragma unroll
    for (int fn = 0; fn < 4; fn++)
#pragma unroll
      for (int r = 0; r < 4; r++) {
        int li = wm * 64 + fm * 16 + r4 + r;
        int lj = wn * 64 + fn * 16 + cj;
        PR[li * 128 + lj] = accR[fm][fn][r];
        PI[li * 128 + lj] = accI[fm][fn][r];
      }
}

// ---------------------------------------------------------------------------
// K4a: stage-1 reduce: grid (128 rows, 3 tiles, 8 groups), 128 threads.
// ---------------------------------------------------------------------------
__global__ __launch_bounds__(128) void k_reduce1(const float* __restrict__ P,
                                                 float* __restrict__ Q) {
  int r = blockIdx.x, tile = blockIdx.y, g = blockIdx.z, c = threadIdx.x;
  const float* base =
      P + ((size_t)(tile * ZSLABS + g * 32) * 2) * 16384 + r * 128 + c;
  float vR = 0.f, vI = 0.f;
  for (int u = 0; u < 32; u++) {
    vR += base[(size_t)u * 32768];
    vI += base[(size_t)u * 32768 + 16384];
  }
  size_t qidx = ((size_t)(g * 3 + tile) * 128 + r) * 128 + c;
  Q[qidx] = vR;
  Q[qidx + (size_t)8 * 3 * 16384] = vI;
}

// K4b: stage-2: sum 8 groups, hermitize -> A, accumulate ||A||_F^2.
__global__ __launch_bounds__(128) void k_reduce2(const float* __restrict__ Q,
                                                 float* __restrict__ AR,
                                                 float* __restrict__ AI,
                                                 float* __restrict__ sumsq,
                                                 float scale) {
  int r = blockIdx.x, tile = blockIdx.y, c = threadIdx.x;
  float vR = 0.f, vI = 0.f;
#pragma unroll
  for (int g = 0; g < 8; g++) {
    size_t qidx = ((size_t)(g * 3 + tile) * 128 + r) * 128 + c;
    vR += Q[qidx];
    vI += Q[qidx + (size_t)8 * 3 * 16384];
  }
  vR *= scale;
  vI *= scale;
  int i = (tile == 2) ? 128 + r : r;
  int j = (tile == 0) ? c : 128 + c;
  float ss = 0.f;
  bool diagTile = (tile != 1);
  if (!diagTile || c > r) {
    AR[i * 256 + j] = vR;
    AR[j * 256 + i] = vR;
    AI[i * 256 + j] = vI;
    AI[j * 256 + i] = -vI;
    ss = 2.f * (vR * vR + vI * vI);
  } else if (c == r) {
    AR[i * 256 + j] = vR;
    AI[i * 256 + j] = 0.f;
    ss = vR * vR;
  }
#pragma unroll
  for (int o = 32; o > 0; o >>= 1) ss += __shfl_down(ss, o);
  __shared__ float w2[2];
  if ((c & 63) == 0) w2[c >> 6] = ss;
  __syncthreads();
  if (c == 0) atomicAdd(sumsq, w2[0] + w2[1]);
}

// ---------------------------------------------------------------------------
// Newton-Schulz complex matmuls, k-split-4: 1024 threads (16 waves =
// 4 waves/SIMD at 1 block/CU) — 4x the latency hiding of the 256-thread
// version (R8: ~7 us/dispatch, 1 wave/SIMD, latency-bound).
// Each k-quarter (sub = t>>8) accumulates 64 k-steps; LDS-reduce at end.
// ---------------------------------------------------------------------------
__global__ __launch_bounds__(1024) void k_csq(
    const float* __restrict__ XR, const float* __restrict__ XI,
    float* __restrict__ YR, float* __restrict__ YI,
    float* __restrict__ sumsqY, int accumNorm) {
  __shared__ float rp[16][256][2];
  __shared__ float cpT[16][258][2];
  __shared__ float pacc[3][256][2];
  __shared__ float w16[16];
  int t = threadIdx.x;
  int bi = blockIdx.x >> 4, bj = blockIdx.x & 15;
  {
    int r = t >> 6, c = (t & 63) * 4;
    const float4 vr = *(const float4*)&XR[(bi * 16 + r) * 256 + c];
    const float4 vi = *(const float4*)&XI[(bi * 16 + r) * 256 + c];
    rp[r][c + 0][0] = vr.x; rp[r][c + 1][0] = vr.y;
    rp[r][c + 2][0] = vr.z; rp[r][c + 3][0] = vr.w;
    rp[r][c + 0][1] = vi.x; rp[r][c + 1][1] = vi.y;
    rp[r][c + 2][1] = vi.z; rp[r][c + 3][1] = vi.w;
    int row = t >> 2, c0 = (t & 3) * 4;
    const float4 wr = *(const float4*)&XR[row * 256 + bj * 16 + c0];
    const float4 wi = *(const float4*)&XI[row * 256 + bj * 16 + c0];
    cpT[c0 + 0][row][0] = wr.x; cpT[c0 + 1][row][0] = wr.y;
    cpT[c0 + 2][row][0] = wr.z; cpT[c0 + 3][row][0] = wr.w;
    cpT[c0 + 0][row][1] = wi.x; cpT[c0 + 1][row][1] = wi.y;
    cpT[c0 + 2][row][1] = wi.z; cpT[c0 + 3][row][1] = wi.w;
  }
  __syncthreads();
  int sub = t >> 8, tt = t & 255, ty = tt >> 4, tx = tt & 15;
  float sR = 0.f, sI = 0.f;
  int k0 = sub * 64;
#pragma unroll 8
  for (int k = k0; k < k0 + 64; k++) {
    float xr = rp[ty][k][0], xi = rp[ty][k][1];
    float yr = cpT[tx][k][0], yi = cpT[tx][k][1];
    sR = fmaf(xr, yr, sR);
    sR = fmaf(-xi, yi, sR);
    sI = fmaf(xr, yi, sI);
    sI = fmaf(xi, yr, sI);
  }
  if (sub) {
    pacc[sub - 1][tt][0] = sR;
    pacc[sub - 1][tt][1] = sI;
  }
  __syncthreads();
  float v = 0.f;
  if (sub == 0) {
    sR += (pacc[0][tt][0] + pacc[1][tt][0]) + pacc[2][tt][0];
    sI += (pacc[0][tt][1] + pacc[1][tt][1]) + pacc[2][tt][1];
    int i = bi * 16 + ty, j = bj * 16 + tx;
    YR[i * 256 + j] = sR;
    YI[i * 256 + j] = sI;
    if (accumNorm) v = sR * sR + sI * sI;
  }
#pragma unroll
  for (int o = 32; o > 0; o >>= 1) v += __shfl_down(v, o);
  if ((t & 63) == 0) w16[t >> 6] = v;
  __syncthreads();
  if (t == 0 && accumNorm)
    atomicAdd(sumsqY, (w16[0] + w16[1]) + (w16[2] + w16[3]));
}

// Z = aC*X - bC*(X@Y); same k-split-4 structure.
// mode 0: first iter ON RAW A (norm-folding). mode 1: 2x-x^3. mode 2: 1.5-NS.
// finalTrace: accumulate out += -0.5*sum(A .* Z) instead of writing Z.
__global__ __launch_bounds__(1024) void k_cupd(
    const float* __restrict__ XR, const float* __restrict__ XI,
    const float* __restrict__ YR, const float* __restrict__ YI,
    float* __restrict__ ZR, float* __restrict__ ZI,
    const float* __restrict__ scalars, int mode,
    const float* __restrict__ AR, const float* __restrict__ AI,
    float* __restrict__ out, int finalTrace) {
  __shared__ float rp[16][256][2];
  __shared__ float cpT[16][258][2];
  __shared__ float pacc[3][256][2];
  __shared__ float w16[16];
  int t = threadIdx.x;
  int bi = blockIdx.x >> 4, bj = blockIdx.x & 15;
  {
    int r = t >> 6, c = (t & 63) * 4;
    const float4 vr = *(const float4*)&XR[(bi * 16 + r) * 256 + c];
    const float4 vi = *(const float4*)&XI[(bi * 16 + r) * 256 + c];
    rp[r][c + 0][0] = vr.x; rp[r][c + 1][0] = vr.y;
    rp[r][c + 2][0] = vr.z; rp[r][c + 3][0] = vr.w;
    rp[r][c + 0][1] = vi.x; rp[r][c + 1][1] = vi.y;
    rp[r][c + 2][1] = vi.z; rp[r][c + 3][1] = vi.w;
    int row = t >> 2, c0 = (t & 3) * 4;
    const float4 wr = *(const float4*)&YR[row * 256 + bj * 16 + c0];
    const float4 wi = *(const float4*)&YI[row * 256 + bj * 16 + c0];
    cpT[c0 + 0][row][0] = wr.x; cpT[c0 + 1][row][0] = wr.y;
    cpT[c0 + 2][row][0] = wr.z; cpT[c0 + 3][row][0] = wr.w;
    cpT[c0 + 0][row][1] = wi.x; cpT[c0 + 1][row][1] = wi.y;
    cpT[c0 + 2][row][1] = wi.z; cpT[c0 + 3][row][1] = wi.w;
  }
  __syncthreads();
  int sub = t >> 8, tt = t & 255, ty = tt >> 4, tx = tt & 15;
  float sR = 0.f, sI = 0.f;
  int k0 = sub * 64;
#pragma unroll 8
  for (int k = k0; k < k0 + 64; k++) {
    float xr = rp[ty][k][0], xi = rp[ty][k][1];
    float yr = cpT[tx][k][0], yi = cpT[tx][k][1];
    sR = fmaf(xr, yr, sR);
    sR = fmaf(-xi, yi, sR);
    sI = fmaf(xr, yi, sI);
    sI = fmaf(xi, yr, sI);
  }
  if (sub) {
    pacc[sub - 1][tt][0] = sR;
    pacc[sub - 1][tt][1] = sI;
  }
  __syncthreads();
  float v = 0.f;
  if (sub == 0) {
    sR += (pacc[0][tt][0] + pacc[1][tt][0]) + pacc[2][tt][0];
    sI += (pacc[0][tt][1] + pacc[1][tt][1]) + pacc[2][tt][1];
    float aC, bC;
    if (mode == 0) {
      float f2 = scalars[0];
      float f = sqrtf(f2);
      float Rhat = 1.41421356f * sqrtf(scalars[1]) / f2;
      float g = 1.0f / (1.75f * Rhat);
      aC = 1.5f * g / f;
      float gf = g / f;
      bC = 0.5f * gf * gf * gf;
    } else if (mode == 1) {
      aC = 2.0f;
      bC = 1.0f;
    } else {
      aC = 1.5f;
      bC = 0.5f;
    }
    int idx = (bi * 16 + ty) * 256 + bj * 16 + tx;
    float zr = aC * XR[idx] - bC * sR;
    float zi = aC * XI[idx] - bC * sI;
    if (!finalTrace) {
      ZR[idx] = zr;
      ZI[idx] = zi;
    } else {
      v = AR[idx] * zr + AI[idx] * zi;
    }
  }
#pragma unroll
  for (int o = 32; o > 0; o >>= 1) v += __shfl_down(v, o);
  if ((t & 63) == 0) w16[t >> 6] = v;
  __syncthreads();
  if (t == 0 && finalTrace)
    atomicAdd(out, -0.5f * ((w16[0] + w16[1]) + (w16[2] + w16[3])));
}

// ---------------------------------------------------------------------------
extern "C" void kernel_launch(void* const* d_in, const int* in_sizes, int n_in,
                              void* d_out, int out_size, void* d_ws,
                              size_t ws_size, hipStream_t stream) {
  const float* x1 = (const float*)d_in[0];
  const float* x0 = (const float*)d_in[1];
  const float* W1 = (const float*)d_in[2];
  const float* b1 = (const float*)d_in[3];
  const float* W2 = (const float*)d_in[4];
  const float* b2 = (const float*)d_in[5];
  const float* W3 = (const float*)d_in[6];
  const float* b3 = (const float*)d_in[7];
  (void)n_in;
  (void)out_size;
  (void)ws_size;

  const int B = in_sizes[0] / 8;       // 65536
  const int total = 2 * B;             // 131072
  const int totalKb = total / 32;      // 4096
  const int kbPer = totalKb / ZSLABS;  // 16

  char* ws = (char*)d_ws;
  size_t off = 0;
  auto carve = [&](size_t bytes) -> void* {
    off = (off + 255) & ~(size_t)255;
    void* p = ws + off;
    off += bytes;
    return p;
  };
  float* hz = (float*)carve((size_t)total * 16 * 4);              // 8.4 MB
  _Float16* Ach = (_Float16*)carve((size_t)totalKb * 16384 * 2);  // 134 MB
  float* P = (float*)carve((size_t)3 * ZSLABS * 2 * 16384 * 4);   // 100.7 MB
  float* Q = (float*)carve((size_t)2 * 8 * 3 * 16384 * 4);        // 3.1 MB
  float* scalars = (float*)carve(256);  // [0]=sumsq(A), [1]=sumsq(A^2)
  float* AR = (float*)carve(256 * 256 * 4);
  float* AI = (float*)carve(256 * 256 * 4);
  float* XR = (float*)carve(256 * 256 * 4);
  float* XI = (float*)carve(256 * 256 * 4);
  float* YR = (float*)carve(256 * 256 * 4);
  float* YI = (float*)carve(256 * 256 * 4);
  float* ZR = (float*)carve(256 * 256 * 4);
  float* ZI = (float*)carve(256 * 256 * 4);

  k_mlp<<<(total + 255) / 256, 256, 0, stream>>>(
      x1, x0, W1, b1, W2, b2, W3, b3, hz, B, scalars, (float*)d_out);
  k_gen<<<totalKb, 256, 0, stream>>>(hz, Ach);
  k_gemm<<<dim3(3, ZSLABS), 256, 0, stream>>>(Ach, P, kbPer);
  k_reduce1<<<dim3(128, 3, 8), 128, 0, stream>>>(P, Q);
  k_reduce2<<<dim3(128, 3), 128, 0, stream>>>(Q, AR, AI, scalars,
                                              1.0f / (256.0f * (float)B));

  // NS schedule: 1x clamp(1.5-NS, rescaled, raw-A norm-folded)
  // + 6x (2x - x^3) + 4x (1.5-NS); trace fused into the last update.
  // Truncation calibration (R4: M=69 -> 6.1e-4 => err ~ 2.9/M^2):
  // M = (1.5/1.75)*2^6*1.5^4 = 278 -> ~3.8e-5, ~8x margin. R8 (M=833)
  // passed with absmax 0.0. Do NOT shorten further without recalibrating.
  const int NIT = 11;
  float *cR = AR, *cI = AI, *nR = XR, *nI = XI;
  for (int it = 0; it < NIT; it++) {
    int mode = (it == 0) ? 0 : (it <= 6 ? 1 : 2);
    int fin = (it == NIT - 1) ? 1 : 0;
    k_csq<<<256, 1024, 0, stream>>>(cR, cI, YR, YI, scalars + 1, it == 0);
    k_cupd<<<256, 1024, 0, stream>>>(cR, cI, YR, YI, nR, nI, scalars, mode, AR,
                                     AI, (float*)d_out, fin);
    if (it == 0) {
      cR = XR; cI = XI; nR = ZR; nI = ZI;
    } else {
      std::swap(cR, nR);
      std::swap(cI, nI);
    }
  }
}